// Round 19
// baseline (179.793 us; speedup 1.0000x reference)
//
#include <hip/hip_runtime.h>
#include <hip/hip_bf16.h>
#include <math.h>

#define NNODES 8192
#define NEDGES 98304

#define TPNORM 0.20412414523193154f      // 1/sqrt(24)
#define INV_SQRT8 0.35355339059327373f   // 1/sqrt(8)
#define QT0S (1.0f/24.0f)                // dot-norm * tp-norm folded
#define QT1S 0.024056261216234406f       // 1/(24*sqrt(3))
#define EMB_C 26.6692997f                // 1.14136*e^2*sqrt(10)
#define STEPI 3.6666666666666665f        // 11/3

// ---- f32 workspace layout (dword offsets) ----
#define WS_NF    0
#define WS_POS   327680
#define WS_WQ0   352256
#define WS_WQ1   352512
#define WS_FCK1  352576
#define WS_FCK2  352896
#define WS_FCV1  371328
#define WS_FCV2  371648
#define WS_WD00  390080
#define WS_WD11  390336
#define WS_FCP1  390400
#define WS_FCP2  391040
#define WS_CVT_END 464768
#define WS_FLAG   464768
#define WS_NODEX  464784
#define WS_NODEQ  792464
#define WS_ZINV  1120144
#define WS_EXPV  1128336
#define WS_ATT   1226640
#define WS_COEF  1554320
#define WS_P3    1652624
#define WS_W2TK  1947536
#define WS_W2TV  1956752
#define WS_WPT   1965968
#define WS_CNT   1968528
#define WS_ROWPTR 1976720
#define WS_CURSOR 1984920
#define WS_EORDER 1993112
#define WS_VFLATB 2091416
// end 4057496 dwords = 16.23 MB

// K/V MFMA fragment tables live in the WS_P3 region (only needed during
// k_edge_tp; k_edge_p overwrites P3 afterwards). 4 tables (Kh,Kl,Vh,Vl)
// of 18432 u16 each = 36864 dwords total (P3 region is 294912 dwords).
#define WS_TBL  WS_P3

using s8v = __attribute__((ext_vector_type(8))) short;   // 8 bf16 (4 VGPRs)
using f4v = __attribute__((ext_vector_type(4))) float;

__device__ __forceinline__ short f2bf(float f){
    unsigned u = __float_as_uint(f);
    unsigned r = (u + 0x7fffu + ((u >> 16) & 1u)) >> 16;
    return (short)r;
}
__device__ __forceinline__ float bfbits2f(unsigned short u){
    return __uint_as_float(((unsigned int)u) << 16);
}

__device__ __forceinline__ float sus_f(float x){
    return x > 0.f ? __expf(-__fdividef(1.f, x)) : 0.f;
}

// per-block dtype detection (Wq0 ~ N(0,1), 256 samples) — deterministic,
// every block computes the same answer; removes the k_detect launch.
__device__ __forceinline__ int block_flag(const void* __restrict__ wq0raw){
    __shared__ int cb;
    if (threadIdx.x == 0) cb = 0;
    __syncthreads();
    const unsigned short* ph = (const unsigned short*)wq0raw;
    float v = bfbits2f(ph[threadIdx.x]);
    float a = fabsf(v);
    if (v == v && a > 1e-3f && a < 64.f) atomicAdd(&cb, 1);
    __syncthreads();
    return (cb >= 200) ? 1 : 0;
}

__device__ __forceinline__ float cvt_in(const void* __restrict__ src, int i, int isb){
    return isb ? bfbits2f(((const unsigned short*)src)[i])
               : ((const float*)src)[i];
}

__device__ __forceinline__ void edge_geom(const float* __restrict__ pos,
                                          int s, int d,
                                          float su[3], float emb[10], float& cut)
{
    float ev[3];
#pragma unroll
    for (int c = 0; c < 3; ++c)
        ev[c] = pos[s*3+c] - pos[d*3+c];
    float l2 = ev[0]*ev[0] + ev[1]*ev[1] + ev[2]*ev[2] + 1e-12f;
    float elen = sqrtf(l2);
    float inv = __fdividef(1.f, elen);
#pragma unroll
    for (int c = 0; c < 3; ++c) su[c] = ev[c]*inv;
    float le = elen * STEPI;
#pragma unroll
    for (int k = 0; k < 10; ++k){
        float diff = le - (float)(k+1);
        emb[k] = EMB_C * sus_f(diff + 1.f) * sus_f(1.f - diff);
    }
    cut = sus_f(10.f * (1.f - elen*(1.f/3.f)));
}

// ---------------- K0: convert + hist + table prep, all fused ----------------
// blocks 0..383  : CSR histogram + 8-wide input conversion (+ block0 persists flag)
// blocks 384..691: table prep reading RAW weights with inline conversion
__global__ __launch_bounds__(256)
void k_convert_all(const void* __restrict__ nf,   const void* __restrict__ pos,
                   const void* __restrict__ wq0,  const void* __restrict__ wq1,
                   const void* __restrict__ fck1, const void* __restrict__ fck2,
                   const void* __restrict__ fcv1, const void* __restrict__ fcv2,
                   const void* __restrict__ wd00, const void* __restrict__ wd11,
                   const void* __restrict__ fcp1, const void* __restrict__ fcp2,
                   float* __restrict__ dst,
                   const int* __restrict__ edst,  int* __restrict__ cnt)
{
    const int isb = block_flag(wq0);
    const int tid = threadIdx.x;
    if (blockIdx.x >= 384){
        // ---- table prep (78848 jobs over 308 blocks) ----
        int idx = (blockIdx.x - 384)*256 + tid;
        if (idx < 5120){
            unsigned short* wpt  = (unsigned short*)(dst + WS_WPT);
            int c = idx >> 6, h = idx & 63;
            unsigned short v = 0;
            if (c < 72){
                int io = c / 3, o = c - io*3;
                int col = (io < 16) ? (io*32 + o) : (512 + (io-16)*32 + o);
                v = (unsigned short)f2bf(cvt_in(fcp2, h*1152 + col, isb));
            }
            wpt[idx] = v;
            return;
        }
        int i2 = idx - 5120;
        if (i2 >= 73728) return;
        int p = i2 / 18432;
        int r = i2 - p*18432;
        int t = r >> 9;
        int l = (r >> 3) & 63;
        int j = r & 7;
        int k = (l >> 4)*8 + j;
        int col = t*16 + (l & 15);
        const void* srcw = (p < 2) ? fck2 : fcv2;
        float wv = cvt_in(srcw, k*576 + col, isb);
        short hi = f2bf(wv);
        unsigned short v;
        if (p & 1) v = (unsigned short)f2bf(wv - bfbits2f((unsigned short)hi));
        else       v = (unsigned short)hi;
        ((unsigned short*)(dst + WS_TBL))[i2] = v;
        return;
    }
    // ---- fused CSR histogram (blocks 0..383 cover all 98304 edges) ----
    {
        int e = blockIdx.x*256 + tid;
        atomicAdd(&cnt[edst[e]], 1);
    }
    if (blockIdx.x == 0 && tid == 0) ((int*)(dst + WS_FLAG))[0] = isb;
    int v = blockIdx.x*256 + tid;
    if (v >= WS_CVT_END/8) return;      // 58096 jobs
    int idx = v*8;
    const void* src; int local;
    if      (idx < WS_POS)  { src = nf;   local = idx; }
    else if (idx < WS_WQ0)  { src = pos;  local = idx - WS_POS; }
    else if (idx < WS_WQ1)  { src = wq0;  local = idx - WS_WQ0; }
    else if (idx < WS_FCK1) { src = wq1;  local = idx - WS_WQ1; }
    else if (idx < WS_FCK2) { src = fck1; local = idx - WS_FCK1; }
    else if (idx < WS_FCV1) { src = fck2; local = idx - WS_FCK2; }
    else if (idx < WS_FCV2) { src = fcv1; local = idx - WS_FCV1; }
    else if (idx < WS_WD00) { src = fcv2; local = idx - WS_FCV2; }
    else if (idx < WS_WD11) { src = wd00; local = idx - WS_WD00; }
    else if (idx < WS_FCP1) { src = wd11; local = idx - WS_WD11; }
    else if (idx < WS_FCP2) { src = fcp1; local = idx - WS_FCP1; }
    else                    { src = fcp2; local = idx - WS_FCP2; }
    float out[8];
    if (isb){
        const unsigned short* p = (const unsigned short*)src + local;
        s8v hv = *(const s8v*)p;
#pragma unroll
        for (int j=0;j<8;j++) out[j] = bfbits2f((unsigned short)hv[j]);
    } else {
        const float* p = (const float*)src + local;
        f4v a = *(const f4v*)p;
        f4v b = *(const f4v*)(p+4);
#pragma unroll
        for (int j=0;j<4;j++){ out[j] = a[j]; out[4+j] = b[j]; }
    }
    f4v o0 = {out[0],out[1],out[2],out[3]};
    f4v o1 = {out[4],out[5],out[6],out[7]};
    *(f4v*)(dst + idx)     = o0;
    *(f4v*)(dst + idx + 4) = o1;
}

// ---------------- CSR build: scan ----------------
__global__ __launch_bounds__(1024)
void k_scan(const int* __restrict__ cnt, int* __restrict__ rowptr, int* __restrict__ cursor)
{
    __shared__ int sdata[1024];
    int tid = threadIdx.x;
    int base = tid*8;
    int loc[8]; int s = 0;
#pragma unroll
    for (int i=0;i<8;i++){ loc[i] = s; s += cnt[base+i]; }
    sdata[tid] = s;
    __syncthreads();
    for (int off=1; off<1024; off<<=1){
        int t = (tid >= off) ? sdata[tid-off] : 0;
        __syncthreads();
        sdata[tid] += t;
        __syncthreads();
    }
    int excl = sdata[tid] - s;
#pragma unroll
    for (int i=0;i<8;i++){
        int v = excl + loc[i];
        rowptr[base+i] = v;
        cursor[base+i] = v;
    }
    if (tid == 1023) rowptr[8192] = sdata[1023];
}

// ---------------- scatter (blocks 0..383) + node prep (blocks 384..415) -------
__global__ __launch_bounds__(256)
void k_scatter_np(const int* __restrict__ edst, int* __restrict__ cursor,
                  int* __restrict__ eorder, float* __restrict__ ws)
{
    __shared__ float q0w[256], d00[256], q1w[64], d11[64];
    const int tid = threadIdx.x;
    if (blockIdx.x < 384){
        int e = blockIdx.x*256 + tid;
        int p = atomicAdd(&cursor[edst[e]], 1);
        eorder[p] = e;
        return;
    }
    // ---- node prep (32 blocks) ----
    q0w[tid] = ws[WS_WQ0 + tid];
    d00[tid] = ws[WS_WD00 + tid];
    if (tid < 64){ q1w[tid] = ws[WS_WQ1 + tid]; d11[tid] = ws[WS_WD11 + tid]; }
    __syncthreads();
    int n = (blockIdx.x - 384)*256 + tid;
    const float* fb = ws + WS_NF + n*40;
    float x0[16], x1[24];
#pragma unroll
    for (int i=0;i<16;i++) x0[i]=fb[i];
#pragma unroll
    for (int i=0;i<24;i++) x1[i]=fb[16+i];
    float q0[16];
#pragma unroll
    for (int o=0;o<16;o++){
        float a=0.f;
#pragma unroll
        for (int i=0;i<16;i++) a += x0[i]*q0w[i*16+o];
        q0[o] = 0.25f*a;
    }
    float q1[24];
#pragma unroll
    for (int o=0;o<8;o++){
        float a0=0.f,a1=0.f,a2=0.f;
#pragma unroll
        for (int i=0;i<8;i++){
            float w = q1w[i*8+o];
            a0 += x1[i*3+0]*w; a1 += x1[i*3+1]*w; a2 += x1[i*3+2]*w;
        }
        q1[o*3+0]=INV_SQRT8*a0; q1[o*3+1]=INV_SQRT8*a1; q1[o*3+2]=INV_SQRT8*a2;
    }
    float* xb = ws + WS_NODEX + n*40;
#pragma unroll
    for (int i=0;i<16;i++) xb[i]=x0[i];
#pragma unroll
    for (int i=0;i<24;i++) xb[16+i]=x1[i];
    float* qb = ws + WS_NODEQ + n*40;
#pragma unroll
    for (int j=0;j<16;j++){
        float a=0.f;
#pragma unroll
        for (int i=0;i<16;i++) a += q0[i]*d00[i*16+j];
        qb[j] = QT0S*a;
    }
#pragma unroll
    for (int j=0;j<8;j++){
        float a0=0.f,a1=0.f,a2=0.f;
#pragma unroll
        for (int i=0;i<8;i++){
            float w = d11[i*8+j];
            a0 += q1[i*3+0]*w; a1 += q1[i*3+1]*w; a2 += q1[i*3+2]*w;
        }
        qb[16+j*3+0]=QT1S*a0; qb[16+j*3+1]=QT1S*a1; qb[16+j*3+2]=QT1S*a2;
    }
}

// ---------------- K2: fused edge K+V pass via MFMA (128 edges/block) ----------
// Round-2-verified 128-edge g-loop geometry + round-15-verified LDS B-staging.
// 4 waves x 32 edges (2 groups of 16). XT stride 128.
// XT slots: 0..15 x0 | 16..39 x1 | 40..47 x1s | 48..50 su | 51 cut | 52..61 emb
__global__ __launch_bounds__(256, 3)
void k_edge_tp(const int* __restrict__ esrc, const int* __restrict__ edst,
               float* __restrict__ ws)
{
    __shared__ __align__(16) float XT[62*128];           // 31 KB
    __shared__ float w1s[640];                           // K W1 then V W1
    __shared__ __align__(16) unsigned short BT[2][4096]; // 16 KB dbuf B-chunks
    const int tid = threadIdx.x;
    for (int i = tid; i < 640; i += 256)
        w1s[i] = (i < 320) ? ws[WS_FCK1 + i] : ws[WS_FCV1 + i - 320];
    const int ebase = blockIdx.x*128;

    // ---- front-end: stage 128 edges ----
    if (tid < 128){
        int e = ebase + tid;
        int s = esrc[e], d = edst[e];
        float su[3], emb[10], cut;
        edge_geom(ws + WS_POS, s, d, su, emb, cut);
        XT[48*128+tid]=su[0]; XT[49*128+tid]=su[1]; XT[50*128+tid]=su[2];
        XT[51*128+tid]=cut;
#pragma unroll
        for (int b=0;b<10;b++) XT[(52+b)*128+tid]=emb[b];
    } else {
        int el = tid - 128;               // 128 jobs: full x-rows
        int s = esrc[ebase + el];
        const f4v* xv4 = (const f4v*)(ws + WS_NODEX + s*40);
        float xr[40];
#pragma unroll
        for (int v4=0; v4<10; ++v4){
            f4v t = xv4[v4];
#pragma unroll
            for (int r=0;r<4;r++) xr[v4*4+r]=t[r];
        }
#pragma unroll
        for (int i=0;i<40;i++) XT[i*128 + el] = xr[i];
    }
    __syncthreads();
    if (tid < 128){
        float s0 = XT[48*128+tid], s1 = XT[49*128+tid], s2 = XT[50*128+tid];
#pragma unroll
        for (int i=0;i<8;i++)
            XT[(40+i)*128+tid] = XT[(16+i*3)*128+tid]*s0
                               + XT[(17+i*3)*128+tid]*s1
                               + XT[(18+i*3)*128+tid]*s2;
    }
    __syncthreads();

    const int lane = tid & 63, w = tid >> 6;
    const int m = lane & 15, quad = lane >> 4;
    const int wloc = w*32;
    const unsigned short* tbl = (const unsigned short*)(ws + WS_TBL);
    const f4v zero = {0.f,0.f,0.f,0.f};
    const int e0 = tid*16;                // u16 index within 4096-elem chunk

#define STAGE_LOAD(ch_) { const unsigned short* sp_ = srcbase + (ch_)*2048; \
                          sr0 = *(const s8v*)(sp_); sr1 = *(const s8v*)(sp_+8); }
#define STAGE_WRITE(d_) { *(s8v*)(&BT[d_][e0]) = sr0; *(s8v*)(&BT[d_][e0+8]) = sr1; }

#pragma unroll 1
    for (int pass = 0; pass < 2; ++pass){
        const unsigned short* th  = tbl + pass*36864;
        const unsigned short* tlo = th + 18432;
        const int w1off = pass*320;
        const unsigned short* srcbase = (e0 < 2048) ? (th + e0) : (tlo + (e0 - 2048));
        s8v sr0, sr1;

        // ---- A fragments (2 groups): hk hi/lo, A[row=m][k=quad*8+j] ----
        s8v ah[2], al[2];
#pragma unroll
        for (int g=0; g<2; ++g){
            float er[10];
#pragma unroll
            for (int b=0;b<10;b++) er[b] = XT[(52+b)*128 + wloc + g*16 + m];
#pragma unroll
            for (int j=0;j<8;j++){
                int h = quad*8 + j;
                float sacc = 0.f;
#pragma unroll
                for (int b=0;b<10;b++) sacc += er[b]*w1s[w1off + b*32 + h];
                float sl = __fdividef(sacc, 1.f + __expf(-sacc));
                short hi = f2bf(sl);
                ah[g][j] = hi;
                al[g][j] = f2bf(sl - bfbits2f((unsigned short)hi));
            }
        }

        float acc0[2][4], at8[2][4], au0[2][4], au1[2][4], au2[2][4];
#pragma unroll
        for (int g=0;g<2;g++)
#pragma unroll
            for (int r=0;r<4;r++){
                acc0[g][r]=0.f; at8[g][r]=0.f;
                au0[g][r]=0.f; au1[g][r]=0.f; au2[g][r]=0.f;
            }

        // ---- prologue: stage chunk 0 (protect BT from prev-pass readers) ----
        __syncthreads();
        STAGE_LOAD(0)
        STAGE_WRITE(0)

        // ---- w00: chunks 0..3 (tiles 0..15), factor x0[t] ----
        for (int ch=0; ch<4; ++ch){
            __syncthreads();
            STAGE_LOAD(ch+1)
            const unsigned short* bb = &BT[ch&1][0];
#pragma unroll
            for (int tl=0; tl<4; ++tl){
                int t = ch*4 + tl;
                s8v bh = *(const s8v*)(bb + tl*512 + lane*8);
                s8v bl = *(const s8v*)(bb + 2048 + tl*512 + lane*8);
#pragma unroll
                for (int g=0; g<2; ++g){
                    f4v c1 = __builtin_amdgcn_mfma_f32_16x16x32_bf16(ah[g], bl, zero, 0,0,0);
                    f4v c2 = __builtin_amdgcn_mfma_f32_16x16x32_bf16(al[g], bh, zero, 0,0,0);
                    c2 = __builtin_amdgcn_mfma_f32_16x16x32_bf16(ah[g], bh, c2, 0,0,0);
                    f4v xv = *(const f4v*)(&XT[t*128 + wloc + g*16 + quad*4]);
#pragma unroll
                    for (int r=0;r<4;r++) acc0[g][r] += xv[r]*(c1[r]+c2[r]);
                }
            }
            STAGE_WRITE((ch+1)&1)
        }
        // ---- w11: chunks 4..5 (tiles 16..23), factor x1s (slots 40..47) ----
        for (int ch=4; ch<6; ++ch){
            __syncthreads();
            STAGE_LOAD(ch+1)
            const unsigned short* bb = &BT[ch&1][0];
#pragma unroll
            for (int tl=0; tl<4; ++tl){
                int t = ch*4 + tl;
                s8v bh = *(const s8v*)(bb + tl*512 + lane*8);
                s8v bl = *(const s8v*)(bb + 2048 + tl*512 + lane*8);
#pragma unroll
                for (int g=0; g<2; ++g){
                    f4v c1 = __builtin_amdgcn_mfma_f32_16x16x32_bf16(ah[g], bl, zero, 0,0,0);
                    f4v c2 = __builtin_amdgcn_mfma_f32_16x16x32_bf16(al[g], bh, zero, 0,0,0);
                    c2 = __builtin_amdgcn_mfma_f32_16x16x32_bf16(ah[g], bh, c2, 0,0,0);
                    f4v xv = *(const f4v*)(&XT[(24+t)*128 + wloc + g*16 + quad*4]);
#pragma unroll
                    for (int r=0;r<4;r++) acc0[g][r] += xv[r]*(c1[r]+c2[r]);
                }
            }
            STAGE_WRITE((ch+1)&1)
        }
        // ---- w01: chunks 6..7 (tiles 24..31) -> t8; i = (t-24)*2 + (m>>3) ----
        for (int ch=6; ch<8; ++ch){
            __syncthreads();
            STAGE_LOAD(ch+1)
            const unsigned short* bb = &BT[ch&1][0];
#pragma unroll
            for (int tl=0; tl<4; ++tl){
                int t = ch*4 + tl;
                s8v bh = *(const s8v*)(bb + tl*512 + lane*8);
                s8v bl = *(const s8v*)(bb + 2048 + tl*512 + lane*8);
                int islot = (t-24)*2 + (m>>3);
#pragma unroll
                for (int g=0; g<2; ++g){
                    f4v c1 = __builtin_amdgcn_mfma_f32_16x16x32_bf16(ah[g], bl, zero, 0,0,0);
                    f4v c2 = __builtin_amdgcn_mfma_f32_16x16x32_bf16(al[g], bh, zero, 0,0,0);
                    c2 = __builtin_amdgcn_mfma_f32_16x16x32_bf16(ah[g], bh, c2, 0,0,0);
                    f4v xv = *(const f4v*)(&XT[islot*128 + wloc + g*16 + quad*4]);
#pragma unroll
                    for (int r=0;r<4;r++) at8[g][r] += xv[r]*(c1[r]+c2[r]);
                }
            }
            STAGE_WRITE((ch+1)&1)
        }
        // ---- w10: chunk 8 (tiles 32..35) -> u[d]; i = (t-32)*2 + (m>>3) ----
        {
            __syncthreads();
            const unsigned short* bb = &BT[0][0];   // 8&1 == 0
#pragma unroll
            for (int tl=0; tl<4; ++tl){
                int t = 32 + tl;
                s8v bh = *(const s8v*)(bb + tl*512 + lane*8);
                s8v bl = *(const s8v*)(bb + 2048 + tl*512 + lane*8);
                int ib = 16 + ((t-32)*2 + (m>>3))*3;
#pragma unroll
                for (int g=0; g<2; ++g){
                    f4v c1 = __builtin_amdgcn_mfma_f32_16x16x32_bf16(ah[g], bl, zero, 0,0,0);
                    f4v c2 = __builtin_amdgcn_mfma_f32_16x16x32_bf16(al[g], bh, zero, 0,0,0);
                    c2 = __builtin_amdgcn_mfma_f32_16x16x32_bf16(ah[g], bh, c2, 0,0,0);
                    f4v x0v = *(const f4v*)(&XT[(ib+0)*128 + wloc + g*16 + quad*4]);
                    f4v x1v = *(const f4v*)(&XT[(ib+1)*128 + wloc + g*16 + quad*4]);
                    f4v x2v = *(const f4v*)(&XT[(ib+2)*128 + wloc + g*16 + quad*4]);
#pragma unroll
                    for (int r=0;r<4;r++){
                        float cc = c1[r]+c2[r];
                        au0[g][r] += x0v[r]*cc;
                        au1[g][r] += x1v[r]*cc;
                        au2[g][r] += x2v[r]*cc;
                    }
                }
            }
        }

        if (pass == 0){
            // ---- K epilogue: dot with q(dst) read from global (L2), reduce ----
#pragma unroll
            for (int g=0; g<2; ++g){
#pragma unroll
                for (int r=0;r<4;r++){
                    int el = wloc + g*16 + quad*4 + r;
                    int d = edst[ebase + el];
                    const float* qr = ws + WS_NODEQ + d*40;
                    int o = m & 7;
                    float q10 = qr[16+o*3+0], q11 = qr[16+o*3+1], q12 = qr[16+o*3+2];
                    float suq = XT[48*128+el]*q10 + XT[49*128+el]*q11 + XT[50*128+el]*q12;
                    float pd = qr[m]*acc0[g][r]
                             + at8[g][r]*suq
                             + au0[g][r]*q10 + au1[g][r]*q11 + au2[g][r]*q12;
                    pd += __shfl_xor(pd, 1);
                    pd += __shfl_xor(pd, 2);
                    pd += __shfl_xor(pd, 4);
                    pd += __shfl_xor(pd, 8);
                    if (m == 0)
                        ws[WS_EXPV + ebase + el] = XT[51*128+el]*__expf(pd);
                }
            }
        } else {
            // ---- V epilogue: combine i-halves, write f16 vflat ----
            _Float16* vfb = (_Float16*)(ws + WS_VFLATB);
#pragma unroll
            for (int g=0; g<2; ++g){
#pragma unroll
                for (int r=0;r<4;r++){
                    int el = wloc + g*16 + quad*4 + r;
                    size_t base = (size_t)(ebase+el)*40;
                    float t8v = at8[g][r] + __shfl_xor(at8[g][r], 8);
                    float u0 = au0[g][r] + __shfl_xor(au0[g][r], 8);
                    float u1 = au1[g][r] + __shfl_xor(au1[g][r], 8);
                    float u2 = au2[g][r] + __shfl_xor(au2[g][r], 8);
                    vfb[base + m] = (_Float16)acc0[g][r];
                    if (m < 8){
                        vfb[base+16+m*3+0] = (_Float16)(u0 + t8v*XT[48*128+el]);
                        vfb[base+16+m*3+1] = (_Float16)(u1 + t8v*XT[49*128+el]);
                        vfb[base+16+m*3+2] = (_Float16)(u2 + t8v*XT[50*128+el]);
                    }
                }
            }
        }
    }
#undef STAGE_LOAD
#undef STAGE_WRITE
}

// ---------------- K3: fused z + coef + att gather (wave per node) ----------------
// 8-way unrolled edge loop (same accumulation order, 8x MLP).
__global__ __launch_bounds__(256)
void k_att(float* __restrict__ ws)
{
    int nw = (blockIdx.x*256 + threadIdx.x) >> 6;   // node = global wave id
    int lane = threadIdx.x & 63;
    const int* rowptr = (const int*)(ws + WS_ROWPTR);
    const int* eorder = (const int*)(ws + WS_EORDER);
    int a = rowptr[nw], b = rowptr[nw+1];
    // z sum: lane-parallel
    float zs = 0.f;
    for (int j = a + lane; j < b; j += 64) zs += ws[WS_EXPV + eorder[j]];
#pragma unroll
    for (int off=1; off<64; off<<=1) zs += __shfl_xor(zs, off);
    float zinv = (zs == 0.f) ? 1.f : __fdividef(1.f, zs);
    // accumulate att cols (lane = col, 40 active), 8-way unrolled
    const _Float16* vfb = (const _Float16*)(ws + WS_VFLATB);
    float acc = 0.f;
    int j = a;
    for (; j + 7 < b; j += 8){
        int ee[8]; float cc[8];
#pragma unroll
        for (int u=0;u<8;u++) ee[u] = eorder[j+u];
#pragma unroll
        for (int u=0;u<8;u++) cc[u] = sqrtf(ws[WS_EXPV + ee[u]]*zinv) * TPNORM;
        if (lane < 40){
            float vv[8];
#pragma unroll
            for (int u=0;u<8;u++) vv[u] = (float)vfb[(size_t)ee[u]*40 + lane];
#pragma unroll
            for (int u=0;u<8;u++) acc += cc[u]*vv[u];
        }
    }
    for (; j < b; ++j){
        int e = eorder[j];
        float coef = sqrtf(ws[WS_EXPV + e]*zinv) * TPNORM;
        if (lane < 40) acc += coef * (float)vfb[(size_t)e*40 + lane];
    }
    if (lane < 40) ws[WS_ATT + nw*40 + lane] = acc;
}

// ------- silu A-fragment builder, SPLIT precision: hk = ah + al (bf16 pair) -------
__device__ __forceinline__ void build_A2(const float* __restrict__ w1, int w1stride,
                                         const float emb[10], int quad, int hbase,
                                         s8v& ah, s8v& al)
{
#pragma unroll
    for (int j=0;j<8;j++){
        int h = hbase + quad*8 + j;
        float sacc = 0.f;
#pragma unroll
        for (int b=0;b<10;b++) sacc += emb[b]*w1[b*w1stride + h];
        float sl = __fdividef(sacc, 1.f + __expf(-sacc));
        short hi = f2bf(sl);
        float rem = sl - bfbits2f((unsigned short)hi);
        ah[j] = hi;
        al[j] = f2bf(rem);
    }
}

// ---------------- K4: fcp psi pass (MFMA, K=64, 72 useful cols) ----------------
// Round-16/17/18 passing body (coalesced block-wide ATT staging, (256,6)).
__global__ __launch_bounds__(256, 6)
void k_edge_p(const int* __restrict__ esrc, const int* __restrict__ edst,
              float* __restrict__ ws)
{
    __shared__ float w1p[640];
    __shared__ __align__(16) float AT[48*64];    // 12 KB
    __shared__ float PG[14*64];                  // 3.5 KB
    const int tid = threadIdx.x;
    for (int i=tid;i<640;i+=256) w1p[i] = ws[WS_FCP1 + i];
    const int ebase = blockIdx.x*64;

    if (tid < 64){
        int e = ebase + tid;
        int sg = esrc[e], dg = edst[e];
        float sug[3], embg[10], cutg;
        edge_geom(ws + WS_POS, sg, dg, sug, embg, cutg);
        PG[0*64+tid]=sug[0]; PG[1*64+tid]=sug[1]; PG[2*64+tid]=sug[2];
        PG[3*64+tid]=cutg;
#pragma unroll
        for (int b=0;b<10;b++) PG[(4+b)*64+tid]=embg[b];
    } else if (tid < 192){
        int idx = tid - 64;               // 128 jobs: half ATT rows
        int el = idx >> 1, hf = idx & 1;
        int s = esrc[ebase + el];
        const f4v* av4 = (const f4v*)(ws + WS_ATT + s*40 + hf*20);
        float ar[20];
#pragma unroll
        for (int v4=0; v4<5; ++v4){
            f4v t = av4[v4];
#pragma unroll
            for (int r=0;r<4;r++) ar[v4*4+r]=t[r];
        }
#pragma unroll
        for (int i=0;i<20;i++) AT[(hf*20+i)*64 + el] = ar[i];
    }
    __syncthreads();
    if (tid < 64){
        float s0 = PG[0*64+tid], s1 = PG[1*64+tid], s2 = PG[2*64+tid];
#pragma unroll
        for (int i1=0;i1<8;i1++)
            AT[(40+i1)*64+tid] = AT[(16+i1*3)*64+tid]*s0
                               + AT[(17+i1*3)*64+tid]*s1
                               + AT[(18+i1*3)*64+tid]*s2;
    }
    __syncthreads();

    const int wid = tid>>6, lane = tid&63;
    const int m = lane&15, quad = lane>>4;
    const int el0 = wid*16;

    float emb[10];
#pragma unroll
    for (int b=0;b<10;b++) emb[b] = PG[(4+b)*64 + el0 + m];

    s8v a0h, a0l, a1h, a1l;
    build_A2(w1p, 64, emb, quad, 0,  a0h, a0l);
    build_A2(w1p, 64, emb, quad, 32, a1h, a1l);
    const unsigned short* wpt = (const unsigned short*)(ws + WS_WPT);
    const f4v zero = {0.f,0.f,0.f,0.f};
    float pa[4][3];
#pragma unroll
    for (int r=0;r<4;r++){ pa[r][0]=0.f; pa[r][1]=0.f; pa[r][2]=0.f; }
#pragma unroll
    for (int ch=0; ch<5; ++ch){
        int col = ch*16 + m;
        s8v b0 = *(const s8v*)(wpt + col*64 + quad*8);
        s8v b1 = *(const s8v*)(wpt + col*64 + 32 + quad*8);
        f4v c = __builtin_amdgcn_mfma_f32_16x16x32_bf16(a0l, b0, zero, 0, 0, 0);
        c = __builtin_amdgcn_mfma_f32_16x16x32_bf16(a1l, b1, c, 0, 0, 0);
        c = __builtin_amdgcn_mfma_f32_16x16x32_bf16(a0h, b0, c, 0, 0, 0);
        c = __builtin_amdgcn_mfma_f32_16x16x32_bf16(a1h, b1, c, 0, 0, 0);
        bool valid = col < 72;
        int io = valid ? ((col*2731) >> 13) : 0;
        int o = col - io*3;
        int row = (io < 16) ? io : (io + 24);    // su-dot rows live at 40..47
        f4v xv = *(const f4v*)(&AT[row*64 + el0 + quad*4]);
#pragma unroll
        for (int r=0;r<4;r++){
            float vv = valid ? xv[r]*c[r] : 0.f;
            pa[r][0] += (o==0) ? vv : 0.f;
            pa[r][1] += (o==1) ? vv : 0.f;
            pa[r][2] += (o==2) ? vv : 0.f;
        }
    }
#pragma unroll
    for (int off=1; off<16; off<<=1){
#pragma unroll
        for (int r=0;r<4;r++){
            pa[r][0] += __shfl_xor(pa[r][0], off);
            pa[r][1] += __shfl_xor(pa[r][1], off);
            pa[r][2] += __shfl_xor(pa[r][2], off);
        }
    }
    if (m == 0){
#pragma unroll
        for (int r=0;r<4;r++){
            int er = el0 + quad*4 + r;
            float sc = PG[3*64 + er] * TPNORM;
#pragma unroll
            for (int k=0;k<3;k++) ws[WS_P3 + (size_t)(ebase+er)*3 + k] = sc*pa[r][k];
        }
    }
}

// ---------------- K5: pot gather + curl + store (wave per node) ----------------
__global__ __launch_bounds__(256)
void k_potfin(float* __restrict__ ws, void* __restrict__ out)
{
    int nw = (blockIdx.x*256 + threadIdx.x) >> 6;   // node = global wave id
    int lane = threadIdx.x & 63;
    const int* rowptr = (const int*)(ws + WS_ROWPTR);
    const int* eorder = (const int*)(ws + WS_EORDER);
    int a = rowptr[nw], b = rowptr[nw+1];
    float s0=0.f, s1=0.f, s2=0.f;
    for (int j = a + lane; j < b; j += 64){
        int e = eorder[j];
        s0 += ws[WS_P3 + (size_t)e*3 + 0];
        s1 += ws[WS_P3 + (size_t)e*3 + 1];
        s2 += ws[WS_P3 + (size_t)e*3 + 2];
    }
#pragma unroll
    for (int off=1; off<64; off<<=1){
        s0 += __shfl_xor(s0, off);
        s1 += __shfl_xor(s1, off);
        s2 += __shfl_xor(s2, off);
    }
    int isb = ((const int*)(ws + WS_FLAG))[0];
    if (lane < 40){
        float v = ws[WS_ATT + (size_t)nw*40 + lane];
        if (lane == 0) v += 0.1f*(s2-s1);
        if (lane == 1) v += 0.1f*(s0-s2);
        if (lane == 2) v += 0.1f*(s1-s0);
        if (isb) ((__hip_bfloat16*)out)[(size_t)nw*40+lane] = __float2bfloat16(v);
        else     ((float*)out)[(size_t)nw*40+lane] = v;
    }
}

extern "C" void kernel_launch(void* const* d_in, const int* in_sizes, int n_in,
                              void* d_out, int out_size, void* d_ws, size_t ws_size,
                              hipStream_t stream)
{
    float* ws = (float*)d_ws;
    const int* esrc = (const int*)d_in[2];
    const int* edst = (const int*)d_in[3];

    hipMemsetAsync(ws + WS_CNT, 0, 8192*sizeof(int), stream);

    k_convert_all<<<692, 256, 0, stream>>>(
        d_in[0], d_in[1], d_in[4], d_in[5], d_in[6], d_in[7],
        d_in[8], d_in[9], d_in[10], d_in[11], d_in[12], d_in[13],
        ws, edst, (int*)(ws + WS_CNT));

    k_scan<<<1, 1024, 0, stream>>>((const int*)(ws + WS_CNT),
                                   (int*)(ws + WS_ROWPTR), (int*)(ws + WS_CURSOR));
    k_scatter_np<<<416, 256, 0, stream>>>(edst, (int*)(ws + WS_CURSOR),
                                          (int*)(ws + WS_EORDER), ws);

    k_edge_tp<<<NEDGES/128, 256, 0, stream>>>(esrc, edst, ws);
    k_att<<<(NNODES*64)/256, 256, 0, stream>>>(ws);
    k_edge_p<<<NEDGES/64, 256, 0, stream>>>(esrc, edst, ws);
    k_potfin<<<(NNODES*64)/256, 256, 0, stream>>>(ws, d_out);
}

// Round 20
// 178.534 us; speedup vs baseline: 1.0071x; 1.0071x over previous
//
#include <hip/hip_runtime.h>
#include <hip/hip_bf16.h>
#include <math.h>

#define NNODES 8192
#define NEDGES 98304

#define TPNORM 0.20412414523193154f      // 1/sqrt(24)
#define INV_SQRT8 0.35355339059327373f   // 1/sqrt(8)
#define QT0S (1.0f/24.0f)                // dot-norm * tp-norm folded
#define QT1S 0.024056261216234406f       // 1/(24*sqrt(3))
#define EMB_C 26.6692997f                // 1.14136*e^2*sqrt(10)
#define STEPI 3.6666666666666665f        // 11/3

// ---- f32 workspace layout (dword offsets) ----
#define WS_NF    0
#define WS_POS   327680
#define WS_WQ0   352256
#define WS_WQ1   352512
#define WS_FCK1  352576
#define WS_FCK2  352896
#define WS_FCV1  371328
#define WS_FCV2  371648
#define WS_WD00  390080
#define WS_WD11  390336
#define WS_FCP1  390400
#define WS_FCP2  391040
#define WS_CVT_END 464768
#define WS_FLAG   464768
#define WS_NODEX  464784
#define WS_NODEQ  792464
#define WS_ZINV  1120144
#define WS_EXPV  1128336
#define WS_ATT   1226640
#define WS_COEF  1554320
#define WS_P3    1652624
#define WS_W2TK  1947536
#define WS_W2TV  1956752
#define WS_WPT   1965968
#define WS_CNT   1968528
#define WS_ROWPTR 1976720
#define WS_CURSOR 1984920
#define WS_EORDER 1993112
#define WS_VFLATB 2091416
// end 4057496 dwords = 16.23 MB

// K/V MFMA fragment tables live in the WS_P3 region (only needed during
// k_edge_tp; k_edge_p overwrites P3 afterwards). 4 tables (Kh,Kl,Vh,Vl)
// of 18432 u16 each = 36864 dwords total (P3 region is 294912 dwords).
#define WS_TBL  WS_P3

using s8v = __attribute__((ext_vector_type(8))) short;   // 8 bf16 (4 VGPRs)
using f4v = __attribute__((ext_vector_type(4))) float;

__device__ __forceinline__ short f2bf(float f){
    unsigned u = __float_as_uint(f);
    unsigned r = (u + 0x7fffu + ((u >> 16) & 1u)) >> 16;
    return (short)r;
}
__device__ __forceinline__ float bfbits2f(unsigned short u){
    return __uint_as_float(((unsigned int)u) << 16);
}

__device__ __forceinline__ float sus_f(float x){
    return x > 0.f ? __expf(-__fdividef(1.f, x)) : 0.f;
}

// per-block dtype detection (Wq0 ~ N(0,1), 256 samples) — deterministic,
// every block computes the same answer; removes the k_detect launch.
__device__ __forceinline__ int block_flag(const void* __restrict__ wq0raw){
    __shared__ int cb;
    if (threadIdx.x == 0) cb = 0;
    __syncthreads();
    const unsigned short* ph = (const unsigned short*)wq0raw;
    float v = bfbits2f(ph[threadIdx.x]);
    float a = fabsf(v);
    if (v == v && a > 1e-3f && a < 64.f) atomicAdd(&cb, 1);
    __syncthreads();
    return (cb >= 200) ? 1 : 0;
}

__device__ __forceinline__ float cvt_in(const void* __restrict__ src, int i, int isb){
    return isb ? bfbits2f(((const unsigned short*)src)[i])
               : ((const float*)src)[i];
}

__device__ __forceinline__ void edge_geom(const float* __restrict__ pos,
                                          int s, int d,
                                          float su[3], float emb[10], float& cut)
{
    float ev[3];
#pragma unroll
    for (int c = 0; c < 3; ++c)
        ev[c] = pos[s*3+c] - pos[d*3+c];
    float l2 = ev[0]*ev[0] + ev[1]*ev[1] + ev[2]*ev[2] + 1e-12f;
    float elen = sqrtf(l2);
    float inv = __fdividef(1.f, elen);
#pragma unroll
    for (int c = 0; c < 3; ++c) su[c] = ev[c]*inv;
    float le = elen * STEPI;
#pragma unroll
    for (int k = 0; k < 10; ++k){
        float diff = le - (float)(k+1);
        emb[k] = EMB_C * sus_f(diff + 1.f) * sus_f(1.f - diff);
    }
    cut = sus_f(10.f * (1.f - elen*(1.f/3.f)));
}

// ---------------- K0: convert + hist + table prep, all fused ----------------
// blocks 0..383  : CSR histogram + 8-wide input conversion (+ block0 persists flag)
// blocks 384..691: table prep reading RAW weights with inline conversion
__global__ __launch_bounds__(256)
void k_convert_all(const void* __restrict__ nf,   const void* __restrict__ pos,
                   const void* __restrict__ wq0,  const void* __restrict__ wq1,
                   const void* __restrict__ fck1, const void* __restrict__ fck2,
                   const void* __restrict__ fcv1, const void* __restrict__ fcv2,
                   const void* __restrict__ wd00, const void* __restrict__ wd11,
                   const void* __restrict__ fcp1, const void* __restrict__ fcp2,
                   float* __restrict__ dst,
                   const int* __restrict__ edst,  int* __restrict__ cnt)
{
    const int isb = block_flag(wq0);
    const int tid = threadIdx.x;
    if (blockIdx.x >= 384){
        // ---- table prep (78848 jobs over 308 blocks) ----
        int idx = (blockIdx.x - 384)*256 + tid;
        if (idx < 5120){
            unsigned short* wpt  = (unsigned short*)(dst + WS_WPT);
            int c = idx >> 6, h = idx & 63;
            unsigned short v = 0;
            if (c < 72){
                int io = c / 3, o = c - io*3;
                int col = (io < 16) ? (io*32 + o) : (512 + (io-16)*32 + o);
                v = (unsigned short)f2bf(cvt_in(fcp2, h*1152 + col, isb));
            }
            wpt[idx] = v;
            return;
        }
        int i2 = idx - 5120;
        if (i2 >= 73728) return;
        int p = i2 / 18432;
        int r = i2 - p*18432;
        int t = r >> 9;
        int l = (r >> 3) & 63;
        int j = r & 7;
        int k = (l >> 4)*8 + j;
        int col = t*16 + (l & 15);
        const void* srcw = (p < 2) ? fck2 : fcv2;
        float wv = cvt_in(srcw, k*576 + col, isb);
        short hi = f2bf(wv);
        unsigned short v;
        if (p & 1) v = (unsigned short)f2bf(wv - bfbits2f((unsigned short)hi));
        else       v = (unsigned short)hi;
        ((unsigned short*)(dst + WS_TBL))[i2] = v;
        return;
    }
    // ---- fused CSR histogram (blocks 0..383 cover all 98304 edges) ----
    {
        int e = blockIdx.x*256 + tid;
        atomicAdd(&cnt[edst[e]], 1);
    }
    if (blockIdx.x == 0 && tid == 0) ((int*)(dst + WS_FLAG))[0] = isb;
    int v = blockIdx.x*256 + tid;
    if (v >= WS_CVT_END/8) return;      // 58096 jobs
    int idx = v*8;
    const void* src; int local;
    if      (idx < WS_POS)  { src = nf;   local = idx; }
    else if (idx < WS_WQ0)  { src = pos;  local = idx - WS_POS; }
    else if (idx < WS_WQ1)  { src = wq0;  local = idx - WS_WQ0; }
    else if (idx < WS_FCK1) { src = wq1;  local = idx - WS_WQ1; }
    else if (idx < WS_FCK2) { src = fck1; local = idx - WS_FCK1; }
    else if (idx < WS_FCV1) { src = fck2; local = idx - WS_FCK2; }
    else if (idx < WS_FCV2) { src = fcv1; local = idx - WS_FCV1; }
    else if (idx < WS_WD00) { src = fcv2; local = idx - WS_FCV2; }
    else if (idx < WS_WD11) { src = wd00; local = idx - WS_WD00; }
    else if (idx < WS_FCP1) { src = wd11; local = idx - WS_WD11; }
    else if (idx < WS_FCP2) { src = fcp1; local = idx - WS_FCP1; }
    else                    { src = fcp2; local = idx - WS_FCP2; }
    float out[8];
    if (isb){
        const unsigned short* p = (const unsigned short*)src + local;
        s8v hv = *(const s8v*)p;
#pragma unroll
        for (int j=0;j<8;j++) out[j] = bfbits2f((unsigned short)hv[j]);
    } else {
        const float* p = (const float*)src + local;
        f4v a = *(const f4v*)p;
        f4v b = *(const f4v*)(p+4);
#pragma unroll
        for (int j=0;j<4;j++){ out[j] = a[j]; out[4+j] = b[j]; }
    }
    f4v o0 = {out[0],out[1],out[2],out[3]};
    f4v o1 = {out[4],out[5],out[6],out[7]};
    *(f4v*)(dst + idx)     = o0;
    *(f4v*)(dst + idx + 4) = o1;
}

// ---------------- CSR build: scan ----------------
__global__ __launch_bounds__(1024)
void k_scan(const int* __restrict__ cnt, int* __restrict__ rowptr, int* __restrict__ cursor)
{
    __shared__ int sdata[1024];
    int tid = threadIdx.x;
    int base = tid*8;
    int loc[8]; int s = 0;
#pragma unroll
    for (int i=0;i<8;i++){ loc[i] = s; s += cnt[base+i]; }
    sdata[tid] = s;
    __syncthreads();
    for (int off=1; off<1024; off<<=1){
        int t = (tid >= off) ? sdata[tid-off] : 0;
        __syncthreads();
        sdata[tid] += t;
        __syncthreads();
    }
    int excl = sdata[tid] - s;
#pragma unroll
    for (int i=0;i<8;i++){
        int v = excl + loc[i];
        rowptr[base+i] = v;
        cursor[base+i] = v;
    }
    if (tid == 1023) rowptr[8192] = sdata[1023];
}

// ---------------- scatter (blocks 0..383) + node prep (blocks 384..415) -------
__global__ __launch_bounds__(256)
void k_scatter_np(const int* __restrict__ edst, int* __restrict__ cursor,
                  int* __restrict__ eorder, float* __restrict__ ws)
{
    __shared__ float q0w[256], d00[256], q1w[64], d11[64];
    const int tid = threadIdx.x;
    if (blockIdx.x < 384){
        int e = blockIdx.x*256 + tid;
        int p = atomicAdd(&cursor[edst[e]], 1);
        eorder[p] = e;
        return;
    }
    // ---- node prep (32 blocks) ----
    q0w[tid] = ws[WS_WQ0 + tid];
    d00[tid] = ws[WS_WD00 + tid];
    if (tid < 64){ q1w[tid] = ws[WS_WQ1 + tid]; d11[tid] = ws[WS_WD11 + tid]; }
    __syncthreads();
    int n = (blockIdx.x - 384)*256 + tid;
    const float* fb = ws + WS_NF + n*40;
    float x0[16], x1[24];
#pragma unroll
    for (int i=0;i<16;i++) x0[i]=fb[i];
#pragma unroll
    for (int i=0;i<24;i++) x1[i]=fb[16+i];
    float q0[16];
#pragma unroll
    for (int o=0;o<16;o++){
        float a=0.f;
#pragma unroll
        for (int i=0;i<16;i++) a += x0[i]*q0w[i*16+o];
        q0[o] = 0.25f*a;
    }
    float q1[24];
#pragma unroll
    for (int o=0;o<8;o++){
        float a0=0.f,a1=0.f,a2=0.f;
#pragma unroll
        for (int i=0;i<8;i++){
            float w = q1w[i*8+o];
            a0 += x1[i*3+0]*w; a1 += x1[i*3+1]*w; a2 += x1[i*3+2]*w;
        }
        q1[o*3+0]=INV_SQRT8*a0; q1[o*3+1]=INV_SQRT8*a1; q1[o*3+2]=INV_SQRT8*a2;
    }
    float* xb = ws + WS_NODEX + n*40;
#pragma unroll
    for (int i=0;i<16;i++) xb[i]=x0[i];
#pragma unroll
    for (int i=0;i<24;i++) xb[16+i]=x1[i];
    float* qb = ws + WS_NODEQ + n*40;
#pragma unroll
    for (int j=0;j<16;j++){
        float a=0.f;
#pragma unroll
        for (int i=0;i<16;i++) a += q0[i]*d00[i*16+j];
        qb[j] = QT0S*a;
    }
#pragma unroll
    for (int j=0;j<8;j++){
        float a0=0.f,a1=0.f,a2=0.f;
#pragma unroll
        for (int i=0;i<8;i++){
            float w = d11[i*8+j];
            a0 += q1[i*3+0]*w; a1 += q1[i*3+1]*w; a2 += q1[i*3+2]*w;
        }
        qb[16+j*3+0]=QT1S*a0; qb[16+j*3+1]=QT1S*a1; qb[16+j*3+2]=QT1S*a2;
    }
}

// ---------------- K2: fused edge K+V pass via MFMA (64 edges/block) ----------
// Round-15/16/17/18 verified structure (LDS dbuf B-chunks, no QD).
// XT slots: 0..15 x0 | 16..39 x1 | 40..47 x1s | 48..50 su | 51 cut | 52..61 emb
__global__ __launch_bounds__(256, 4)
void k_edge_tp(const int* __restrict__ esrc, const int* __restrict__ edst,
               float* __restrict__ ws)
{
    __shared__ __align__(16) float XT[64*64];            // 16 KB
    __shared__ float w1s[640];                           // K W1 then V W1
    __shared__ __align__(16) unsigned short BT[2][4096]; // 16 KB dbuf B-chunks
    const int tid = threadIdx.x;
    for (int i = tid; i < 640; i += 256)
        w1s[i] = (i < 320) ? ws[WS_FCK1 + i] : ws[WS_FCV1 + i - 320];
    const int ebase = blockIdx.x*64;

    // ---- front-end: stage 64 edges ----
    if (tid < 64){
        int e = ebase + tid;
        int s = esrc[e], d = edst[e];
        float su[3], emb[10], cut;
        edge_geom(ws + WS_POS, s, d, su, emb, cut);
        XT[48*64+tid]=su[0]; XT[49*64+tid]=su[1]; XT[50*64+tid]=su[2];
        XT[51*64+tid]=cut;
#pragma unroll
        for (int b=0;b<10;b++) XT[(52+b)*64+tid]=emb[b];
    } else if (tid < 192){
        int idx = tid - 64;               // 128 jobs: half x-rows
        int el = idx >> 1, hf = idx & 1;
        int s = esrc[ebase + el];
        const f4v* xv4 = (const f4v*)(ws + WS_NODEX + s*40 + hf*20);
        float xr[20];
#pragma unroll
        for (int v4=0; v4<5; ++v4){
            f4v t = xv4[v4];
#pragma unroll
            for (int r=0;r<4;r++) xr[v4*4+r]=t[r];
        }
#pragma unroll
        for (int i=0;i<20;i++) XT[(hf*20+i)*64 + el] = xr[i];
    }
    __syncthreads();
    if (tid < 64){
        float s0 = XT[48*64+tid], s1 = XT[49*64+tid], s2 = XT[50*64+tid];
#pragma unroll
        for (int i=0;i<8;i++)
            XT[(40+i)*64+tid] = XT[(16+i*3)*64+tid]*s0
                              + XT[(17+i*3)*64+tid]*s1
                              + XT[(18+i*3)*64+tid]*s2;
    }
    __syncthreads();

    const int lane = tid & 63, w = tid >> 6;
    const int m = lane & 15, quad = lane >> 4;
    const int eloc = w*16;
    const unsigned short* tbl = (const unsigned short*)(ws + WS_TBL);
    const f4v zero = {0.f,0.f,0.f,0.f};
    const int e0 = tid*16;                // u16 index within 4096-elem chunk

#define STAGE_LOAD(ch_) { const unsigned short* sp_ = srcbase + (ch_)*2048; \
                          sr0 = *(const s8v*)(sp_); sr1 = *(const s8v*)(sp_+8); }
#define STAGE_WRITE(d_) { *(s8v*)(&BT[d_][e0]) = sr0; *(s8v*)(&BT[d_][e0+8]) = sr1; }

#define TP_CHAIN(bhsrc_, blsrc_) \
    s8v bh = *(const s8v*)(bhsrc_); \
    s8v bl = *(const s8v*)(blsrc_); \
    f4v c1 = __builtin_amdgcn_mfma_f32_16x16x32_bf16(ah, bl, zero, 0,0,0); \
    f4v c2 = __builtin_amdgcn_mfma_f32_16x16x32_bf16(al, bh, zero, 0,0,0); \
    c2 = __builtin_amdgcn_mfma_f32_16x16x32_bf16(ah, bh, c2, 0,0,0);

#pragma unroll 1
    for (int pass = 0; pass < 2; ++pass){
        const unsigned short* th  = tbl + pass*36864;
        const unsigned short* tlo = th + 18432;
        const int w1off = pass*320;
        const unsigned short* srcbase = (e0 < 2048) ? (th + e0) : (tlo + (e0 - 2048));
        s8v sr0, sr1;

        // ---- A fragment: hk hi/lo, A[row=m][k=quad*8+j] ----
        s8v ah, al;
        {
            float er[10];
#pragma unroll
            for (int b=0;b<10;b++) er[b] = XT[(52+b)*64 + eloc + m];
#pragma unroll
            for (int j=0;j<8;j++){
                int h = quad*8 + j;
                float sacc = 0.f;
#pragma unroll
                for (int b=0;b<10;b++) sacc += er[b]*w1s[w1off + b*32 + h];
                float sl = __fdividef(sacc, 1.f + __expf(-sacc));
                short hi = f2bf(sl);
                ah[j] = hi;
                al[j] = f2bf(sl - bfbits2f((unsigned short)hi));
            }
        }

        float acc0[4], at8[4], au0[4], au1[4], au2[4];
#pragma unroll
        for (int r=0;r<4;r++){ acc0[r]=0.f; at8[r]=0.f; au0[r]=0.f; au1[r]=0.f; au2[r]=0.f; }

        // ---- prologue: stage chunk 0 (protect BT from prev-pass readers) ----
        __syncthreads();
        STAGE_LOAD(0)
        STAGE_WRITE(0)

        // ---- w00: chunks 0..3 (tiles 0..15), factor x0[t] ----
        for (int ch=0; ch<4; ++ch){
            __syncthreads();
            STAGE_LOAD(ch+1)
            const unsigned short* bb = &BT[ch&1][0];
#pragma unroll
            for (int tl=0; tl<4; ++tl){
                int t = ch*4 + tl;
                TP_CHAIN(bb + tl*512 + lane*8, bb + 2048 + tl*512 + lane*8)
                f4v xv = *(const f4v*)(&XT[t*64 + eloc + quad*4]);
#pragma unroll
                for (int r=0;r<4;r++) acc0[r] += xv[r]*(c1[r]+c2[r]);
            }
            STAGE_WRITE((ch+1)&1)
        }
        // ---- w11: chunks 4..5 (tiles 16..23), factor x1s (slots 40..47) ----
        for (int ch=4; ch<6; ++ch){
            __syncthreads();
            STAGE_LOAD(ch+1)
            const unsigned short* bb = &BT[ch&1][0];
#pragma unroll
            for (int tl=0; tl<4; ++tl){
                int t = ch*4 + tl;
                TP_CHAIN(bb + tl*512 + lane*8, bb + 2048 + tl*512 + lane*8)
                f4v xv = *(const f4v*)(&XT[(24+t)*64 + eloc + quad*4]);
#pragma unroll
                for (int r=0;r<4;r++) acc0[r] += xv[r]*(c1[r]+c2[r]);
            }
            STAGE_WRITE((ch+1)&1)
        }
        // ---- w01: chunks 6..7 (tiles 24..31) -> t8; i = (t-24)*2 + (m>>3) ----
        for (int ch=6; ch<8; ++ch){
            __syncthreads();
            STAGE_LOAD(ch+1)
            const unsigned short* bb = &BT[ch&1][0];
#pragma unroll
            for (int tl=0; tl<4; ++tl){
                int t = ch*4 + tl;
                TP_CHAIN(bb + tl*512 + lane*8, bb + 2048 + tl*512 + lane*8)
                int islot = (t-24)*2 + (m>>3);
                f4v xv = *(const f4v*)(&XT[islot*64 + eloc + quad*4]);
#pragma unroll
                for (int r=0;r<4;r++) at8[r] += xv[r]*(c1[r]+c2[r]);
            }
            STAGE_WRITE((ch+1)&1)
        }
        // ---- w10: chunk 8 (tiles 32..35) -> u[d]; i = (t-32)*2 + (m>>3) ----
        {
            __syncthreads();
            const unsigned short* bb = &BT[0][0];   // 8&1 == 0
#pragma unroll
            for (int tl=0; tl<4; ++tl){
                int t = 32 + tl;
                TP_CHAIN(bb + tl*512 + lane*8, bb + 2048 + tl*512 + lane*8)
                int ib = 16 + ((t-32)*2 + (m>>3))*3;
                f4v x0v = *(const f4v*)(&XT[(ib+0)*64 + eloc + quad*4]);
                f4v x1v = *(const f4v*)(&XT[(ib+1)*64 + eloc + quad*4]);
                f4v x2v = *(const f4v*)(&XT[(ib+2)*64 + eloc + quad*4]);
#pragma unroll
                for (int r=0;r<4;r++){
                    float cc = c1[r]+c2[r];
                    au0[r] += x0v[r]*cc;
                    au1[r] += x1v[r]*cc;
                    au2[r] += x2v[r]*cc;
                }
            }
        }

        if (pass == 0){
            // ---- K epilogue: dot with q(dst) read from global (L2), reduce ----
#pragma unroll
            for (int r=0;r<4;r++){
                int el = eloc + quad*4 + r;
                int d = edst[ebase + el];
                const float* qr = ws + WS_NODEQ + d*40;
                int o = m & 7;
                float q10 = qr[16+o*3+0], q11 = qr[16+o*3+1], q12 = qr[16+o*3+2];
                float suq = XT[48*64+el]*q10 + XT[49*64+el]*q11 + XT[50*64+el]*q12;
                float pd = qr[m]*acc0[r]
                         + at8[r]*suq
                         + au0[r]*q10 + au1[r]*q11 + au2[r]*q12;
                pd += __shfl_xor(pd, 1);
                pd += __shfl_xor(pd, 2);
                pd += __shfl_xor(pd, 4);
                pd += __shfl_xor(pd, 8);
                if (m == 0)
                    ws[WS_EXPV + ebase + el] = XT[51*64+el]*__expf(pd);
            }
        } else {
            // ---- V epilogue: combine i-halves, write f16 vflat ----
            _Float16* vfb = (_Float16*)(ws + WS_VFLATB);
#pragma unroll
            for (int r=0;r<4;r++){
                int el = eloc + quad*4 + r;
                size_t base = (size_t)(ebase+el)*40;
                float t8v = at8[r] + __shfl_xor(at8[r], 8);
                float u0 = au0[r] + __shfl_xor(au0[r], 8);
                float u1 = au1[r] + __shfl_xor(au1[r], 8);
                float u2 = au2[r] + __shfl_xor(au2[r], 8);
                vfb[base + m] = (_Float16)acc0[r];
                if (m < 8){
                    vfb[base+16+m*3+0] = (_Float16)(u0 + t8v*XT[48*64+el]);
                    vfb[base+16+m*3+1] = (_Float16)(u1 + t8v*XT[49*64+el]);
                    vfb[base+16+m*3+2] = (_Float16)(u2 + t8v*XT[50*64+el]);
                }
            }
        }
    }
#undef STAGE_LOAD
#undef STAGE_WRITE
#undef TP_CHAIN
}

// ---------------- K3: fused z + coef + att gather (wave per node) ----------------
// 8-way unrolled edge loop (same accumulation order, 8x MLP).
__global__ __launch_bounds__(256)
void k_att(float* __restrict__ ws)
{
    int nw = (blockIdx.x*256 + threadIdx.x) >> 6;   // node = global wave id
    int lane = threadIdx.x & 63;
    const int* rowptr = (const int*)(ws + WS_ROWPTR);
    const int* eorder = (const int*)(ws + WS_EORDER);
    int a = rowptr[nw], b = rowptr[nw+1];
    // z sum: lane-parallel
    float zs = 0.f;
    for (int j = a + lane; j < b; j += 64) zs += ws[WS_EXPV + eorder[j]];
#pragma unroll
    for (int off=1; off<64; off<<=1) zs += __shfl_xor(zs, off);
    float zinv = (zs == 0.f) ? 1.f : __fdividef(1.f, zs);
    // accumulate att cols (lane = col, 40 active), 8-way unrolled
    const _Float16* vfb = (const _Float16*)(ws + WS_VFLATB);
    float acc = 0.f;
    int j = a;
    for (; j + 7 < b; j += 8){
        int ee[8]; float cc[8];
#pragma unroll
        for (int u=0;u<8;u++) ee[u] = eorder[j+u];
#pragma unroll
        for (int u=0;u<8;u++) cc[u] = sqrtf(ws[WS_EXPV + ee[u]]*zinv) * TPNORM;
        if (lane < 40){
            float vv[8];
#pragma unroll
            for (int u=0;u<8;u++) vv[u] = (float)vfb[(size_t)ee[u]*40 + lane];
#pragma unroll
            for (int u=0;u<8;u++) acc += cc[u]*vv[u];
        }
    }
    for (; j < b; ++j){
        int e = eorder[j];
        float coef = sqrtf(ws[WS_EXPV + e]*zinv) * TPNORM;
        if (lane < 40) acc += coef * (float)vfb[(size_t)e*40 + lane];
    }
    if (lane < 40) ws[WS_ATT + nw*40 + lane] = acc;
}

// ------- silu A-fragment builder, SPLIT precision: hk = ah + al (bf16 pair) -------
__device__ __forceinline__ void build_A2(const float* __restrict__ w1, int w1stride,
                                         const float emb[10], int quad, int hbase,
                                         s8v& ah, s8v& al)
{
#pragma unroll
    for (int j=0;j<8;j++){
        int h = hbase + quad*8 + j;
        float sacc = 0.f;
#pragma unroll
        for (int b=0;b<10;b++) sacc += emb[b]*w1[b*w1stride + h];
        float sl = __fdividef(sacc, 1.f + __expf(-sacc));
        short hi = f2bf(sl);
        float rem = sl - bfbits2f((unsigned short)hi);
        ah[j] = hi;
        al[j] = f2bf(rem);
    }
}

// ---------------- K4: fcp psi pass (MFMA, K=64, 72 useful cols) ----------------
// Round-16/17/18 passing body (coalesced block-wide ATT staging, (256,6)).
__global__ __launch_bounds__(256, 6)
void k_edge_p(const int* __restrict__ esrc, const int* __restrict__ edst,
              float* __restrict__ ws)
{
    __shared__ float w1p[640];
    __shared__ __align__(16) float AT[48*64];    // 12 KB
    __shared__ float PG[14*64];                  // 3.5 KB
    const int tid = threadIdx.x;
    for (int i=tid;i<640;i+=256) w1p[i] = ws[WS_FCP1 + i];
    const int ebase = blockIdx.x*64;

    if (tid < 64){
        int e = ebase + tid;
        int sg = esrc[e], dg = edst[e];
        float sug[3], embg[10], cutg;
        edge_geom(ws + WS_POS, sg, dg, sug, embg, cutg);
        PG[0*64+tid]=sug[0]; PG[1*64+tid]=sug[1]; PG[2*64+tid]=sug[2];
        PG[3*64+tid]=cutg;
#pragma unroll
        for (int b=0;b<10;b++) PG[(4+b)*64+tid]=embg[b];
    } else if (tid < 192){
        int idx = tid - 64;               // 128 jobs: half ATT rows
        int el = idx >> 1, hf = idx & 1;
        int s = esrc[ebase + el];
        const f4v* av4 = (const f4v*)(ws + WS_ATT + s*40 + hf*20);
        float ar[20];
#pragma unroll
        for (int v4=0; v4<5; ++v4){
            f4v t = av4[v4];
#pragma unroll
            for (int r=0;r<4;r++) ar[v4*4+r]=t[r];
        }
#pragma unroll
        for (int i=0;i<20;i++) AT[(hf*20+i)*64 + el] = ar[i];
    }
    __syncthreads();
    if (tid < 64){
        float s0 = PG[0*64+tid], s1 = PG[1*64+tid], s2 = PG[2*64+tid];
#pragma unroll
        for (int i1=0;i1<8;i1++)
            AT[(40+i1)*64+tid] = AT[(16+i1*3)*64+tid]*s0
                               + AT[(17+i1*3)*64+tid]*s1
                               + AT[(18+i1*3)*64+tid]*s2;
    }
    __syncthreads();

    const int wid = tid>>6, lane = tid&63;
    const int m = lane&15, quad = lane>>4;
    const int el0 = wid*16;

    float emb[10];
#pragma unroll
    for (int b=0;b<10;b++) emb[b] = PG[(4+b)*64 + el0 + m];

    s8v a0h, a0l, a1h, a1l;
    build_A2(w1p, 64, emb, quad, 0,  a0h, a0l);
    build_A2(w1p, 64, emb, quad, 32, a1h, a1l);
    const unsigned short* wpt = (const unsigned short*)(ws + WS_WPT);
    const f4v zero = {0.f,0.f,0.f,0.f};
    float pa[4][3];
#pragma unroll
    for (int r=0;r<4;r++){ pa[r][0]=0.f; pa[r][1]=0.f; pa[r][2]=0.f; }
#pragma unroll
    for (int ch=0; ch<5; ++ch){
        int col = ch*16 + m;
        s8v b0 = *(const s8v*)(wpt + col*64 + quad*8);
        s8v b1 = *(const s8v*)(wpt + col*64 + 32 + quad*8);
        f4v c = __builtin_amdgcn_mfma_f32_16x16x32_bf16(a0l, b0, zero, 0, 0, 0);
        c = __builtin_amdgcn_mfma_f32_16x16x32_bf16(a1l, b1, c, 0, 0, 0);
        c = __builtin_amdgcn_mfma_f32_16x16x32_bf16(a0h, b0, c, 0, 0, 0);
        c = __builtin_amdgcn_mfma_f32_16x16x32_bf16(a1h, b1, c, 0, 0, 0);
        bool valid = col < 72;
        int io = valid ? ((col*2731) >> 13) : 0;
        int o = col - io*3;
        int row = (io < 16) ? io : (io + 24);    // su-dot rows live at 40..47
        f4v xv = *(const f4v*)(&AT[row*64 + el0 + quad*4]);
#pragma unroll
        for (int r=0;r<4;r++){
            float vv = valid ? xv[r]*c[r] : 0.f;
            pa[r][0] += (o==0) ? vv : 0.f;
            pa[r][1] += (o==1) ? vv : 0.f;
            pa[r][2] += (o==2) ? vv : 0.f;
        }
    }
#pragma unroll
    for (int off=1; off<16; off<<=1){
#pragma unroll
        for (int r=0;r<4;r++){
            pa[r][0] += __shfl_xor(pa[r][0], off);
            pa[r][1] += __shfl_xor(pa[r][1], off);
            pa[r][2] += __shfl_xor(pa[r][2], off);
        }
    }
    if (m == 0){
#pragma unroll
        for (int r=0;r<4;r++){
            int er = el0 + quad*4 + r;
            float sc = PG[3*64 + er] * TPNORM;
#pragma unroll
            for (int k=0;k<3;k++) ws[WS_P3 + (size_t)(ebase+er)*3 + k] = sc*pa[r][k];
        }
    }
}

// ---------------- K5: pot gather + curl + store (wave per node) ----------------
__global__ __launch_bounds__(256)
void k_potfin(float* __restrict__ ws, void* __restrict__ out)
{
    int nw = (blockIdx.x*256 + threadIdx.x) >> 6;   // node = global wave id
    int lane = threadIdx.x & 63;
    const int* rowptr = (const int*)(ws + WS_ROWPTR);
    const int* eorder = (const int*)(ws + WS_EORDER);
    int a = rowptr[nw], b = rowptr[nw+1];
    float s0=0.f, s1=0.f, s2=0.f;
    for (int j = a + lane; j < b; j += 64){
        int e = eorder[j];
        s0 += ws[WS_P3 + (size_t)e*3 + 0];
        s1 += ws[WS_P3 + (size_t)e*3 + 1];
        s2 += ws[WS_P3 + (size_t)e*3 + 2];
    }
#pragma unroll
    for (int off=1; off<64; off<<=1){
        s0 += __shfl_xor(s0, off);
        s1 += __shfl_xor(s1, off);
        s2 += __shfl_xor(s2, off);
    }
    int isb = ((const int*)(ws + WS_FLAG))[0];
    if (lane < 40){
        float v = ws[WS_ATT + (size_t)nw*40 + lane];
        if (lane == 0) v += 0.1f*(s2-s1);
        if (lane == 1) v += 0.1f*(s0-s2);
        if (lane == 2) v += 0.1f*(s1-s0);
        if (isb) ((__hip_bfloat16*)out)[(size_t)nw*40+lane] = __float2bfloat16(v);
        else     ((float*)out)[(size_t)nw*40+lane] = v;
    }
}

extern "C" void kernel_launch(void* const* d_in, const int* in_sizes, int n_in,
                              void* d_out, int out_size, void* d_ws, size_t ws_size,
                              hipStream_t stream)
{
    float* ws = (float*)d_ws;
    const int* esrc = (const int*)d_in[2];
    const int* edst = (const int*)d_in[3];

    hipMemsetAsync(ws + WS_CNT, 0, 8192*sizeof(int), stream);

    k_convert_all<<<692, 256, 0, stream>>>(
        d_in[0], d_in[1], d_in[4], d_in[5], d_in[6], d_in[7],
        d_in[8], d_in[9], d_in[10], d_in[11], d_in[12], d_in[13],
        ws, edst, (int*)(ws + WS_CNT));

    k_scan<<<1, 1024, 0, stream>>>((const int*)(ws + WS_CNT),
                                   (int*)(ws + WS_ROWPTR), (int*)(ws + WS_CURSOR));
    k_scatter_np<<<416, 256, 0, stream>>>(edst, (int*)(ws + WS_CURSOR),
                                          (int*)(ws + WS_EORDER), ws);

    k_edge_tp<<<NEDGES/64, 256, 0, stream>>>(esrc, edst, ws);
    k_att<<<(NNODES*64)/256, 256, 0, stream>>>(ws);
    k_edge_p<<<NEDGES/64, 256, 0, stream>>>(esrc, edst, ws);
    k_potfin<<<(NNODES*64)/256, 256, 0, stream>>>(ws, d_out);
}